// Round 1
// baseline (323.970 us; speedup 1.0000x reference)
//
#include <hip/hip_runtime.h>
#include <cstdint>
#include <cstddef>

// Problem constants: B=2, T=2048, C=960, NH=24, NKV=6, HD=40
// qkv_out = (24+2*6)*40 = 1440 (padded to 1536), proj N = 960 (padded to 1024)

#define DI __device__ __forceinline__

typedef _Float16 f16x8 __attribute__((ext_vector_type(8)));
typedef float f32x4 __attribute__((ext_vector_type(4)));
typedef unsigned short u16;
typedef unsigned int u32;

DI u16 f2h(float f) { _Float16 h = (_Float16)f; return __builtin_bit_cast(u16, h); }
DI float h2f(u16 u) { return (float)__builtin_bit_cast(_Float16, u); }

#define MFMA16(a, b, c) __builtin_amdgcn_mfma_f32_16x16x32_f16(a, b, c, 0, 0, 0)

DI void gload_lds16(const void* g, void* l) {
  __builtin_amdgcn_global_load_lds((const __attribute__((address_space(1))) u32*)g,
                                   (__attribute__((address_space(3))) u32*)l, 16, 0, 0);
}

// ---------------- conversion kernels ----------------

__global__ void cvt_x_kernel(const float* __restrict__ x, u16* __restrict__ o, int n4) {
  int i = blockIdx.x * 256 + threadIdx.x;
  if (i >= n4) return;
  float4 v = ((const float4*)x)[i];
  ushort4 r;
  r.x = f2h(v.x); r.y = f2h(v.y); r.z = f2h(v.z); r.w = f2h(v.w);
  ((ushort4*)o)[i] = r;
}

// convert weight [rows_in][cols] fp32 -> [rows_out][cols] fp16, zero-padding rows.
// optionally pad bias into bo[rows_out].
__global__ void cvt_w_kernel(const float* __restrict__ w, const float* __restrict__ bias,
                             u16* __restrict__ o, float* __restrict__ bo,
                             int rows_in, int rows_out, int cols) {
  int i = blockIdx.x * 256 + threadIdx.x;
  int c4 = cols >> 2;
  int total = rows_out * c4;
  if (i < total) {
    int row = i / c4, c = (i - row * c4) * 4;
    ushort4 r;
    if (row < rows_in) {
      float4 v = *(const float4*)&w[(size_t)row * cols + c];
      r.x = f2h(v.x); r.y = f2h(v.y); r.z = f2h(v.z); r.w = f2h(v.w);
    } else {
      r.x = r.y = r.z = r.w = 0;
    }
    *(ushort4*)&o[(size_t)row * cols + c] = r;
  }
  if (bo != nullptr && i < rows_out) bo[i] = (i < rows_in) ? bias[i] : 0.f;
}

// ---------------- GEMM: C[M][N] = A[M][K] @ B[N][K]^T + bias ----------------
// m97 structure: 128x128 tile, BK=32, 4 waves (2x2), 16x16x32 f16 MFMA,
// global_load_lds width 16, single LDS buffer, 2 barriers per K-step.
// MODE 0: fp16 out (ld = Npad). MODE 1: fp32 out (ld = Nstore, col guard).
template <int MODE>
__global__ __launch_bounds__(256) void gemm_bt(const u16* __restrict__ A, const u16* __restrict__ Bw,
                                               const float* __restrict__ bias, void* __restrict__ outp,
                                               int K, int Npad, int Nstore) {
  __shared__ u16 As[128 * 32];
  __shared__ u16 Bs[128 * 32];
  const int tid = threadIdx.x;
  const int l = tid & 63, w = tid >> 6;
  const int bm = blockIdx.x, bn = blockIdx.y;
  const int wm = w >> 1, wn = w & 1;
  const int la = l & 15, lg = l >> 4;

  const u16* ga = A + (size_t)(bm * 128 + (tid >> 2)) * K + (tid & 3) * 8;
  const u16* gb = Bw + (size_t)(bn * 128 + (tid >> 2)) * K + (tid & 3) * 8;
  void* lA = (void*)(As + (size_t)w * 512);
  void* lB = (void*)(Bs + (size_t)w * 512);

  f32x4 acc[4][4] = {};

  for (int k0 = 0; k0 < K; k0 += 32) {
    __syncthreads();
    gload_lds16(ga, lA);
    gload_lds16(ga + (size_t)64 * K, (char*)lA + 4096);
    gload_lds16(gb, lB);
    gload_lds16(gb + (size_t)64 * K, (char*)lB + 4096);
    ga += 32; gb += 32;
    __syncthreads();
    f16x8 af[4], bf[4];
#pragma unroll
    for (int i = 0; i < 4; i++)
      af[i] = *(const f16x8*)&As[(wm * 64 + i * 16 + la) * 32 + lg * 8];
#pragma unroll
    for (int j = 0; j < 4; j++)
      bf[j] = *(const f16x8*)&Bs[(wn * 64 + j * 16 + la) * 32 + lg * 8];
#pragma unroll
    for (int i = 0; i < 4; i++)
#pragma unroll
      for (int j = 0; j < 4; j++)
        acc[i][j] = MFMA16(af[i], bf[j], acc[i][j]);
  }

  const int rowb = bm * 128 + wm * 64 + lg * 4;
  const int colb = bn * 128 + wn * 64 + la;
#pragma unroll
  for (int j = 0; j < 4; j++) {
    int col = colb + j * 16;
    float bv = (MODE == 1 && col >= Nstore) ? 0.f : bias[col];
#pragma unroll
    for (int i = 0; i < 4; i++) {
#pragma unroll
      for (int r = 0; r < 4; r++) {
        int row = rowb + i * 16 + r;
        float v = acc[i][j][r] + bv;
        if (MODE == 0) {
          ((u16*)outp)[(size_t)row * Npad + col] = f2h(v);
        } else {
          if (col < Nstore) ((float*)outp)[(size_t)row * Nstore + col] = v;
        }
      }
    }
  }
}

// ---------------- RoPE + scatter ----------------
// qkv fp16 [4096][1536] -> q_pad [2][24][2048][64] (rope'd, * 1/sqrt(40), d>=40 zero)
//                          k_pad [2][6][2048][64]  (rope'd, d>=40 zero)
//                          v_t   [2][6][64][2048]  (transposed, d<40 only)
__global__ __launch_bounds__(256) void rope_scatter(const u16* __restrict__ qkv,
                                                    u16* __restrict__ qp, u16* __restrict__ kp,
                                                    u16* __restrict__ vt) {
  const int m = blockIdx.x;  // b*2048 + t
  const int b = m >> 11, t = m & 2047;
  const size_t qkvrow = (size_t)m * 1536;
  for (int i = threadIdx.x; i < 1080; i += 256) {
    if (i < 960) {
      int head = i >> 5, pp = i & 31;  // 30 heads x 32 pair-slots (pad to 64 dims)
      bool isq = head < 24;
      int hh = isq ? head : head - 24;
      u16* dst = isq ? (qp + (((size_t)b * 24 + hh) * 2048 + t) * 64)
                     : (kp + (((size_t)b * 6 + hh) * 2048 + t) * 64);
      if (pp < 20) {
        int col = isq ? (head * 40 + 2 * pp) : (960 + hh * 40 + 2 * pp);
        float x1 = h2f(qkv[qkvrow + col]);
        float x2 = h2f(qkv[qkvrow + col + 1]);
        float inv = powf(10000.f, -(float)pp * 0.05f);  // 10000^(-2*pp/40)
        float th = (float)t * inv;
        float sn = sinf(th), cs = cosf(th);
        float r1 = x1 * cs - x2 * sn;
        float r2 = x1 * sn + x2 * cs;
        if (isq) { r1 *= 0.15811388300841898f; r2 *= 0.15811388300841898f; }
        dst[2 * pp] = f2h(r1);
        dst[2 * pp + 1] = f2h(r2);
      } else {
        dst[2 * pp] = 0;
        dst[2 * pp + 1] = 0;
      }
    } else {
      int j = i - 960;  // 6 heads x 20 pairs of V
      int head = j / 20, pp = j - head * 20;
      int col = 1200 + head * 40 + 2 * pp;
      size_t vb = (((size_t)b * 6 + head) * 64 + 2 * pp) * 2048 + t;
      vt[vb] = qkv[qkvrow + col];
      vt[vb + 2048] = qkv[qkvrow + col + 1];
    }
  }
}

// ---------------- flash attention (causal, GQA) ----------------
// grid: 48 (b*h) x 32 (q-blocks of 64). 4 waves, each owns 16 q-rows.
// KVBLK=32. K tile [32][72] (144B stride: 2-way bank alias = free),
// V^T tile [64][72], P wave-private [16][72].
__global__ __launch_bounds__(256) void attn_kernel(const u16* __restrict__ qp,
                                                   const u16* __restrict__ kp,
                                                   const u16* __restrict__ vt,
                                                   u16* __restrict__ ao) {
  const int bid = blockIdx.x;
  const int qb = bid & 31, bh = bid >> 5;
  const int b = bh / 24, h = bh - b * 24, hk = h >> 2;
  const int tid = threadIdx.x, l = tid & 63, w = tid >> 6;
  const int la = l & 15, lg = l >> 4;

  __shared__ u16 Ks[32 * 72];
  __shared__ u16 Vs[64 * 72];
  __shared__ u16 Ps[4][16 * 72];

  const int q0 = qb * 64 + w * 16;
  const u16* qrow = qp + ((((size_t)b * 24 + h) * 2048) + q0 + la) * 64 + lg * 8;
  f16x8 qf0 = *(const f16x8*)qrow;
  f16x8 qf1 = *(const f16x8*)(qrow + 32);

  f32x4 acc[4] = {};
  float mrun[4], lrun[4];
#pragma unroll
  for (int r = 0; r < 4; r++) { mrun[r] = -1e30f; lrun[r] = 0.f; }

  const u16* kg = kp + ((size_t)b * 6 + hk) * 2048 * 64;
  const u16* vg = vt + ((size_t)b * 6 + hk) * 64 * 2048;
  const int nsteps = (qb + 1) * 2;
  const int kr = tid >> 3, kc = (tid & 7) * 8;
  const int vr = tid >> 2, vc = (tid & 3) * 8;

  for (int s = 0; s < nsteps; ++s) {
    const int kv0 = s * 32;
    __syncthreads();
    *(uint4*)&Ks[kr * 72 + kc] = *(const uint4*)(kg + (size_t)(kv0 + kr) * 64 + kc);
    *(uint4*)&Vs[vr * 72 + vc] = *(const uint4*)(vg + (size_t)vr * 2048 + kv0 + vc);
    __syncthreads();
    if (kv0 > q0 + 15) continue;  // wave-uniform skip (barriers still hit each iter)

    f32x4 z = {0.f, 0.f, 0.f, 0.f};
    f32x4 s0 = MFMA16(qf0, *(const f16x8*)&Ks[la * 72 + lg * 8], z);
    s0 = MFMA16(qf1, *(const f16x8*)&Ks[la * 72 + 32 + lg * 8], s0);
    f32x4 s1 = MFMA16(qf0, *(const f16x8*)&Ks[(la + 16) * 72 + lg * 8], z);
    s1 = MFMA16(qf1, *(const f16x8*)&Ks[(la + 16) * 72 + 32 + lg * 8], s1);

    const int kva = kv0 + la, kvb = kv0 + 16 + la;
    float pm[4], ps[4], al[4];
#pragma unroll
    for (int r = 0; r < 4; r++) {
      int qg = q0 + lg * 4 + r;
      if (kva > qg) s0[r] = -1e30f;
      if (kvb > qg) s1[r] = -1e30f;
      pm[r] = fmaxf(s0[r], s1[r]);
    }
#pragma unroll
    for (int r = 0; r < 4; r++) {
      pm[r] = fmaxf(pm[r], __shfl_xor(pm[r], 1));
      pm[r] = fmaxf(pm[r], __shfl_xor(pm[r], 2));
      pm[r] = fmaxf(pm[r], __shfl_xor(pm[r], 4));
      pm[r] = fmaxf(pm[r], __shfl_xor(pm[r], 8));
    }
#pragma unroll
    for (int r = 0; r < 4; r++) {
      float mn = fmaxf(mrun[r], pm[r]);
      al[r] = __expf(mrun[r] - mn);
      mrun[r] = mn;
      float p0 = __expf(s0[r] - mn);
      float p1 = __expf(s1[r] - mn);
      s0[r] = p0; s1[r] = p1;
      ps[r] = p0 + p1;
    }
#pragma unroll
    for (int r = 0; r < 4; r++) {
      ps[r] += __shfl_xor(ps[r], 1);
      ps[r] += __shfl_xor(ps[r], 2);
      ps[r] += __shfl_xor(ps[r], 4);
      ps[r] += __shfl_xor(ps[r], 8);
      lrun[r] = lrun[r] * al[r] + ps[r];
    }
#pragma unroll
    for (int nt = 0; nt < 4; nt++)
#pragma unroll
      for (int r = 0; r < 4; r++) acc[nt][r] *= al[r];

    u16* pw = &Ps[w][0];
#pragma unroll
    for (int r = 0; r < 4; r++) {
      pw[(lg * 4 + r) * 72 + la] = f2h(s0[r]);
      pw[(lg * 4 + r) * 72 + la + 16] = f2h(s1[r]);
    }
    asm volatile("s_waitcnt lgkmcnt(0)" ::: "memory");
    f16x8 pf = *(const f16x8*)&pw[la * 72 + lg * 8];
#pragma unroll
    for (int nt = 0; nt < 4; nt++) {
      f16x8 vf = *(const f16x8*)&Vs[(la + nt * 16) * 72 + lg * 8];
      acc[nt] = MFMA16(pf, vf, acc[nt]);
    }
  }

  // epilogue: normalize, store d<40 as fp16 into [4096][960]
#pragma unroll
  for (int r = 0; r < 4; r++) {
    int qg = q0 + lg * 4 + r;
    float inv = 1.f / lrun[r];
    size_t ob = ((size_t)(b * 2048 + qg)) * 960 + h * 40;
#pragma unroll
    for (int nt = 0; nt < 3; nt++) {
      int d = nt * 16 + la;
      if (d < 40) ao[ob + d] = f2h(acc[nt][r] * inv);
    }
  }
}

// ---------------- launch ----------------

extern "C" void kernel_launch(void* const* d_in, const int* in_sizes, int n_in,
                              void* d_out, int out_size, void* d_ws, size_t ws_size,
                              hipStream_t stream) {
  const float* x = (const float*)d_in[0];      // [2][2048][960]
  const float* Wqkv = (const float*)d_in[1];   // [1440][960]
  const float* bqkv = (const float*)d_in[2];   // [1440]
  const float* Wproj = (const float*)d_in[3];  // [960][960]
  const float* bproj = (const float*)d_in[4];  // [960]
  float* out = (float*)d_out;                  // [4096][960] fp32

  // workspace layout (~52 MB)
  char* ws = (char*)d_ws;
  u16* xb = (u16*)ws;                                // 4096*960
  u16* wqkvb = xb + (size_t)4096 * 960;              // 1536*960
  u16* wprojb = wqkvb + (size_t)1536 * 960;          // 1024*960
  float* bqp = (float*)(wprojb + (size_t)1024 * 960);// 1536
  u16* qkvb = (u16*)(bqp + 1536);                    // 4096*1536
  u16* qp = qkvb + (size_t)4096 * 1536;              // 2*24*2048*64
  u16* kp = qp + (size_t)2 * 24 * 2048 * 64;         // 2*6*2048*64
  u16* vt = kp + (size_t)2 * 6 * 2048 * 64;          // 2*6*64*2048
  u16* ao = vt + (size_t)2 * 6 * 64 * 2048;          // 4096*960

  // converts
  cvt_x_kernel<<<3840, 256, 0, stream>>>(x, xb, 4096 * 960 / 4);
  cvt_w_kernel<<<1440, 256, 0, stream>>>(Wqkv, bqkv, wqkvb, bqp, 1440, 1536, 960);
  cvt_w_kernel<<<960, 256, 0, stream>>>(Wproj, nullptr, wprojb, nullptr, 960, 1024, 960);

  // QKV projection: [4096][1536] = x @ Wqkv^T + b
  gemm_bt<0><<<dim3(32, 12), 256, 0, stream>>>(xb, wqkvb, bqp, qkvb, 960, 1536, 1536);

  // RoPE + scatter to attention layouts
  rope_scatter<<<4096, 256, 0, stream>>>(qkvb, qp, kp, vt);

  // flash attention
  attn_kernel<<<1536, 256, 0, stream>>>(qp, kp, vt, ao);

  // output projection: [4096][960] = attn @ Wproj^T + b (fp32 out)
  gemm_bt<1><<<dim3(32, 8), 256, 0, stream>>>(ao, wprojb, bproj, out, 960, 1024, 960);
}

// Round 3
// 304.928 us; speedup vs baseline: 1.0624x; 1.0624x over previous
//
#include <hip/hip_runtime.h>
#include <cstdint>
#include <cstddef>

// Problem constants: B=2, T=2048, C=960, NH=24, NKV=6, HD=40
// qkv_out = (24+2*6)*40 = 1440 (padded to 1536), proj N = 960 (padded to 1024)

#define DI __device__ __forceinline__

typedef _Float16 f16x8 __attribute__((ext_vector_type(8)));
typedef _Float16 f16x4 __attribute__((ext_vector_type(4)));
typedef float f32x4 __attribute__((ext_vector_type(4)));
typedef unsigned short u16;
typedef unsigned int u32;

DI u16 f2h(float f) { _Float16 h = (_Float16)f; return __builtin_bit_cast(u16, h); }
DI float h2f(u16 u) { return (float)__builtin_bit_cast(_Float16, u); }

#define MFMA32(a, b, c) __builtin_amdgcn_mfma_f32_16x16x32_f16(a, b, c, 0, 0, 0)
// NOTE: legacy K=16 intrinsic has NO underscore before dtype on this toolchain
#define MFMA16(a, b, c) __builtin_amdgcn_mfma_f32_16x16x16f16(a, b, c, 0, 0, 0)

DI void gload_lds16(const void* g, void* l) {
  __builtin_amdgcn_global_load_lds((const __attribute__((address_space(1))) u32*)g,
                                   (__attribute__((address_space(3))) u32*)l, 16, 0, 0);
}

// ---------------- conversion kernels ----------------

__global__ void cvt_x_kernel(const float* __restrict__ x, u16* __restrict__ o, int n4) {
  int i = blockIdx.x * 256 + threadIdx.x;
  if (i >= n4) return;
  float4 v = ((const float4*)x)[i];
  ushort4 r;
  r.x = f2h(v.x); r.y = f2h(v.y); r.z = f2h(v.z); r.w = f2h(v.w);
  ((ushort4*)o)[i] = r;
}

__global__ void cvt_w_kernel(const float* __restrict__ w, const float* __restrict__ bias,
                             u16* __restrict__ o, float* __restrict__ bo,
                             int rows_in, int rows_out, int cols) {
  int i = blockIdx.x * 256 + threadIdx.x;
  int c4 = cols >> 2;
  int total = rows_out * c4;
  if (i < total) {
    int row = i / c4, c = (i - row * c4) * 4;
    ushort4 r;
    if (row < rows_in) {
      float4 v = *(const float4*)&w[(size_t)row * cols + c];
      r.x = f2h(v.x); r.y = f2h(v.y); r.z = f2h(v.z); r.w = f2h(v.w);
    } else {
      r.x = r.y = r.z = r.w = 0;
    }
    *(ushort4*)&o[(size_t)row * cols + c] = r;
  }
  if (bo != nullptr && i < rows_out) bo[i] = (i < rows_in) ? bias[i] : 0.f;
}

// ---------------- GEMM: C[M][N] = A[M][K] @ B[N][K]^T + bias ----------------
template <int MODE>
__global__ __launch_bounds__(256) void gemm_bt(const u16* __restrict__ A, const u16* __restrict__ Bw,
                                               const float* __restrict__ bias, void* __restrict__ outp,
                                               int K, int Npad, int Nstore) {
  __shared__ u16 As[128 * 32];
  __shared__ u16 Bs[128 * 32];
  const int tid = threadIdx.x;
  const int l = tid & 63, w = tid >> 6;
  const int bm = blockIdx.x, bn = blockIdx.y;
  const int wm = w >> 1, wn = w & 1;
  const int la = l & 15, lg = l >> 4;

  const u16* ga = A + (size_t)(bm * 128 + (tid >> 2)) * K + (tid & 3) * 8;
  const u16* gb = Bw + (size_t)(bn * 128 + (tid >> 2)) * K + (tid & 3) * 8;
  void* lA = (void*)(As + (size_t)w * 512);
  void* lB = (void*)(Bs + (size_t)w * 512);

  f32x4 acc[4][4] = {};

  for (int k0 = 0; k0 < K; k0 += 32) {
    __syncthreads();
    gload_lds16(ga, lA);
    gload_lds16(ga + (size_t)64 * K, (char*)lA + 4096);
    gload_lds16(gb, lB);
    gload_lds16(gb + (size_t)64 * K, (char*)lB + 4096);
    ga += 32; gb += 32;
    __syncthreads();
    f16x8 af[4], bf[4];
#pragma unroll
    for (int i = 0; i < 4; i++)
      af[i] = *(const f16x8*)&As[(wm * 64 + i * 16 + la) * 32 + lg * 8];
#pragma unroll
    for (int j = 0; j < 4; j++)
      bf[j] = *(const f16x8*)&Bs[(wn * 64 + j * 16 + la) * 32 + lg * 8];
#pragma unroll
    for (int i = 0; i < 4; i++)
#pragma unroll
      for (int j = 0; j < 4; j++)
        acc[i][j] = MFMA32(af[i], bf[j], acc[i][j]);
  }

  const int rowb = bm * 128 + wm * 64 + lg * 4;
  const int colb = bn * 128 + wn * 64 + la;
#pragma unroll
  for (int j = 0; j < 4; j++) {
    int col = colb + j * 16;
    float bv = (MODE == 1 && col >= Nstore) ? 0.f : bias[col];
#pragma unroll
    for (int i = 0; i < 4; i++) {
#pragma unroll
      for (int r = 0; r < 4; r++) {
        int row = rowb + i * 16 + r;
        float v = acc[i][j][r] + bv;
        if (MODE == 0) {
          ((u16*)outp)[(size_t)row * Npad + col] = f2h(v);
        } else {
          if (col < Nstore) ((float*)outp)[(size_t)row * Nstore + col] = v;
        }
      }
    }
  }
}

// ---------------- RoPE + scatter ----------------
// qkv fp16 [4096][1536] -> q_pad [2][24][2048][64] (rope'd, * 1/sqrt(40), d>=40 zero)
//                          k_pad [2][6][2048][64]  (rope'd, d>=40 zero)
//                          v_t   [2][6][64][2048]  (transposed, d<40; d in 40..47 zeroed)
__global__ __launch_bounds__(256) void rope_scatter(const u16* __restrict__ qkv,
                                                    u16* __restrict__ qp, u16* __restrict__ kp,
                                                    u16* __restrict__ vt) {
  const int m = blockIdx.x;  // b*2048 + t
  const int b = m >> 11, t = m & 2047;
  const size_t qkvrow = (size_t)m * 1536;
  for (int i = threadIdx.x; i < 1128; i += 256) {
    if (i < 960) {
      int head = i >> 5, pp = i & 31;  // 30 heads x 32 pair-slots (pad to 64 dims)
      bool isq = head < 24;
      int hh = isq ? head : head - 24;
      u16* dst = isq ? (qp + (((size_t)b * 24 + hh) * 2048 + t) * 64)
                     : (kp + (((size_t)b * 6 + hh) * 2048 + t) * 64);
      if (pp < 20) {
        int col = isq ? (head * 40 + 2 * pp) : (960 + hh * 40 + 2 * pp);
        float x1 = h2f(qkv[qkvrow + col]);
        float x2 = h2f(qkv[qkvrow + col + 1]);
        float inv = powf(10000.f, -(float)pp * 0.05f);  // 10000^(-2*pp/40)
        float th = (float)t * inv;
        float sn = sinf(th), cs = cosf(th);
        float r1 = x1 * cs - x2 * sn;
        float r2 = x1 * sn + x2 * cs;
        if (isq) { r1 *= 0.15811388300841898f; r2 *= 0.15811388300841898f; }
        dst[2 * pp] = f2h(r1);
        dst[2 * pp + 1] = f2h(r2);
      } else {
        dst[2 * pp] = 0;
        dst[2 * pp + 1] = 0;
      }
    } else if (i < 1080) {
      int j = i - 960;  // 6 heads x 20 pairs of V
      int head = j / 20, pp = j - head * 20;
      int col = 1200 + head * 40 + 2 * pp;
      size_t vb = (((size_t)b * 6 + head) * 64 + 2 * pp) * 2048 + t;
      vt[vb] = qkv[qkvrow + col];
      vt[vb + 2048] = qkv[qkvrow + col + 1];
    } else {
      int j = i - 1080;  // zero V pad rows d=40..47 (read by PV d-tile 2)
      int head = j >> 3, d = 40 + (j & 7);
      vt[(((size_t)b * 6 + head) * 64 + d) * 2048 + t] = 0;
    }
  }
}

// ---------------- flash attention (causal, GQA), swapped-operand ----------------
// S^T = mfma(A=K, B=Q): lane owns q-column (la), 8 kv rows in regs.
// Softmax: 7 in-lane ops + 2 shfl_xor. P^T stays in registers, feeds
// mfma_f32_16x16x16f16 B-operand directly (PV = V^T x P^T, out^T).
// No LDS, no barriers. Each wave processes q-tile pair (p, 127-p):
// constant 65 kv-chunks per wave -> perfect balance.
__global__ __launch_bounds__(256) void attn_kernel(const u16* __restrict__ qp,
                                                   const u16* __restrict__ kp,
                                                   const u16* __restrict__ vt,
                                                   u16* __restrict__ ao) {
  const int tid = threadIdx.x, l = tid & 63, w = tid >> 6;
  const int la = l & 15, lg = l >> 4;
  const int bid = blockIdx.x;
  const int pg = bid & 15, bh = bid >> 4;  // 16 pair-groups x 48 bh
  const int b = bh / 24, h = bh - b * 24, hk = h >> 2;
  const int p = pg * 4 + w;  // pair index 0..63

  const u16* qbase = qp + ((size_t)b * 24 + h) * 2048 * 64;
  const u16* kg = kp + ((size_t)b * 6 + hk) * 2048 * 64;
  const u16* vg = vt + ((size_t)b * 6 + hk) * 64 * 2048;
  u16* aob = ao + (size_t)b * 2048 * 960 + h * 40;

  for (int ti = 0; ti < 2; ++ti) {
    const int tile = ti == 0 ? p : 127 - p;
    const int q0 = tile * 16;
    const int qg = q0 + la;  // this lane's q column

    const u16* qrow = qbase + (size_t)(q0 + la) * 64 + lg * 8;
    f16x8 qf0 = *(const f16x8*)qrow;
    f16x8 qf1 = *(const f16x8*)(qrow + 32);

    f32x4 acc0 = {}, acc1 = {}, acc2 = {};
    float m = -1e30f, lsum = 0.f;
    const int nch = (tile >> 1) + 1;

    for (int c = 0; c < nch; ++c) {
      const int kv0 = c * 32;
      const u16* kc = kg + (size_t)kv0 * 64 + lg * 8;
      f16x8 k0a = *(const f16x8*)(kc + (size_t)la * 64);
      f16x8 k0b = *(const f16x8*)(kc + (size_t)la * 64 + 32);
      f16x8 k1a = *(const f16x8*)(kc + (size_t)(16 + la) * 64);
      f16x8 k1b = *(const f16x8*)(kc + (size_t)(16 + la) * 64 + 32);

      f32x4 z = {0.f, 0.f, 0.f, 0.f};
      f32x4 s0 = MFMA32(k0a, qf0, z);
      s0 = MFMA32(k0b, qf1, s0);
      f32x4 s1 = MFMA32(k1a, qf0, z);
      s1 = MFMA32(k1b, qf1, s1);

      // mask + in-lane max (lane holds kv = kv0+lg*4+r and +16, one q col)
      float pm = -1e30f;
#pragma unroll
      for (int r = 0; r < 4; r++) {
        int kva = kv0 + lg * 4 + r;
        if (kva > qg) s0[r] = -1e30f;
        if (kva + 16 > qg) s1[r] = -1e30f;
        pm = fmaxf(pm, fmaxf(s0[r], s1[r]));
      }
      pm = fmaxf(pm, __shfl_xor(pm, 16));
      pm = fmaxf(pm, __shfl_xor(pm, 32));

      float mn = fmaxf(m, pm);
      float al = __expf(m - mn);
      m = mn;
      float ps = 0.f;
#pragma unroll
      for (int r = 0; r < 4; r++) {
        s0[r] = __expf(s0[r] - mn);
        s1[r] = __expf(s1[r] - mn);
        ps += s0[r] + s1[r];
      }
      ps += __shfl_xor(ps, 16);
      ps += __shfl_xor(ps, 32);
      lsum = lsum * al + ps;

      f16x4 p0, p1;
#pragma unroll
      for (int r = 0; r < 4; r++) {
        p0[r] = (_Float16)s0[r];
        p1[r] = (_Float16)s1[r];
      }
#pragma unroll
      for (int r = 0; r < 4; r++) {
        acc0[r] *= al; acc1[r] *= al; acc2[r] *= al;
      }

      // PV: out^T[d][q] += V^T[d][kv] * P^T[kv][q], 16x16x16 per 16-kv half
      const u16* vc = vg + (size_t)la * 2048 + kv0 + lg * 4;
      {
        f16x4 v0 = *(const f16x4*)(vc);
        f16x4 v1 = *(const f16x4*)(vc + 16);
        acc0 = MFMA16(v0, p0, acc0);
        acc0 = MFMA16(v1, p1, acc0);
      }
      {
        f16x4 v0 = *(const f16x4*)(vc + (size_t)16 * 2048);
        f16x4 v1 = *(const f16x4*)(vc + (size_t)16 * 2048 + 16);
        acc1 = MFMA16(v0, p0, acc1);
        acc1 = MFMA16(v1, p1, acc1);
      }
      {
        f16x4 v0 = *(const f16x4*)(vc + (size_t)32 * 2048);
        f16x4 v1 = *(const f16x4*)(vc + (size_t)32 * 2048 + 16);
        acc2 = MFMA16(v0, p0, acc2);
        acc2 = MFMA16(v1, p1, acc2);
      }
    }

    // epilogue: lane owns q=q0+la, d = dt*16 + lg*4 + r
    const float inv = 1.f / lsum;
    u16* orow = aob + (size_t)(q0 + la) * 960;
#pragma unroll
    for (int r = 0; r < 4; r++) {
      int d0 = lg * 4 + r;
      orow[d0] = f2h(acc0[r] * inv);
      orow[d0 + 16] = f2h(acc1[r] * inv);
      if (d0 + 32 < 40) orow[d0 + 32] = f2h(acc2[r] * inv);
    }
  }
}

// ---------------- launch ----------------

extern "C" void kernel_launch(void* const* d_in, const int* in_sizes, int n_in,
                              void* d_out, int out_size, void* d_ws, size_t ws_size,
                              hipStream_t stream) {
  const float* x = (const float*)d_in[0];      // [2][2048][960]
  const float* Wqkv = (const float*)d_in[1];   // [1440][960]
  const float* bqkv = (const float*)d_in[2];   // [1440]
  const float* Wproj = (const float*)d_in[3];  // [960][960]
  const float* bproj = (const float*)d_in[4];  // [960]
  float* out = (float*)d_out;                  // [4096][960] fp32

  // workspace layout (~52 MB)
  char* ws = (char*)d_ws;
  u16* xb = (u16*)ws;                                // 4096*960
  u16* wqkvb = xb + (size_t)4096 * 960;              // 1536*960
  u16* wprojb = wqkvb + (size_t)1536 * 960;          // 1024*960
  float* bqp = (float*)(wprojb + (size_t)1024 * 960);// 1536
  u16* qkvb = (u16*)(bqp + 1536);                    // 4096*1536
  u16* qp = qkvb + (size_t)4096 * 1536;              // 2*24*2048*64
  u16* kp = qp + (size_t)2 * 24 * 2048 * 64;         // 2*6*2048*64
  u16* vt = kp + (size_t)2 * 6 * 2048 * 64;          // 2*6*64*2048
  u16* ao = vt + (size_t)2 * 6 * 64 * 2048;          // 4096*960

  // converts
  cvt_x_kernel<<<3840, 256, 0, stream>>>(x, xb, 4096 * 960 / 4);
  cvt_w_kernel<<<1440, 256, 0, stream>>>(Wqkv, bqkv, wqkvb, bqp, 1440, 1536, 960);
  cvt_w_kernel<<<960, 256, 0, stream>>>(Wproj, nullptr, wprojb, nullptr, 960, 1024, 960);

  // QKV projection: [4096][1536] = x @ Wqkv^T + b
  gemm_bt<0><<<dim3(32, 12), 256, 0, stream>>>(xb, wqkvb, bqp, qkvb, 960, 1536, 1536);

  // RoPE + scatter to attention layouts
  rope_scatter<<<4096, 256, 0, stream>>>(qkvb, qp, kp, vt);

  // flash attention (768 blocks x 4 waves, each wave = q-tile pair)
  attn_kernel<<<768, 256, 0, stream>>>(qp, kp, vt, ao);

  // output projection: [4096][960] = attn @ Wproj^T + b (fp32 out)
  gemm_bt<1><<<dim3(32, 8), 256, 0, stream>>>(ao, wprojb, bproj, out, 960, 1024, 960);
}